// Round 4
// baseline (280.178 us; speedup 1.0000x reference)
//
#include <hip/hip_runtime.h>
#include <stdint.h>

// Problem constants (SelfAttention: B=8, C=512, C8=64, W=2048)
#define B_  8
#define C_  512
#define CO_ 64
#define W_  2048
#define R_  640   // stacked projection rows: 64 q + 64 k + 512 v

typedef float f32x4 __attribute__((ext_vector_type(4)));
typedef float f32x16 __attribute__((ext_vector_type(16)));
typedef __bf16 bf16x8 __attribute__((ext_vector_type(8)));
typedef __bf16 bf16x2 __attribute__((ext_vector_type(2)));
typedef unsigned u32x4 __attribute__((ext_vector_type(4)));
typedef unsigned short u16;
typedef u16 u16x8 __attribute__((ext_vector_type(8)));
typedef u16 u16x4 __attribute__((ext_vector_type(4)));

static __device__ __forceinline__ u16 f2b(float f){
  union { float f; unsigned u; } v; v.f = f;
  unsigned r = v.u + 0x7FFFu + ((v.u >> 16) & 1u);  // RNE
  return (u16)(r >> 16);
}
static __device__ __forceinline__ bf16x8 ldb(const u16* p){
  return __builtin_bit_cast(bf16x8, *(const u16x8*)p);
}
static __device__ __forceinline__ f32x4 mfma16(bf16x8 a, bf16x8 b, f32x4 c){
  return __builtin_amdgcn_mfma_f32_16x16x32_bf16(a, b, c, 0, 0, 0);
}
static __device__ __forceinline__ f32x16 mfma32(bf16x8 a, bf16x8 b, f32x16 c){
  return __builtin_amdgcn_mfma_f32_32x32x16_bf16(a, b, c, 0, 0, 0);
}
// v_permlane32_swap_b32: vdst lanes[32:63] <-> vsrc lanes[0:31]
static __device__ __forceinline__ void pl32swap(unsigned &a, unsigned &b){
  asm("v_permlane32_swap_b32 %0, %1" : "+v"(a), "+v"(b));
}
static __device__ __forceinline__ float red_max32(float v){
  unsigned a = __builtin_bit_cast(unsigned, v), b = a;
  pl32swap(a, b);
  return fmaxf(__builtin_bit_cast(float, a), __builtin_bit_cast(float, b));
}
static __device__ __forceinline__ float red_sum32(float v){
  unsigned a = __builtin_bit_cast(unsigned, v), b = a;
  pl32swap(a, b);
  return __builtin_bit_cast(float, a) + __builtin_bit_cast(float, b);
}
static __device__ __forceinline__ unsigned pkbf(float lo, float hi){
  bf16x2 t; t[0] = (__bf16)lo; t[1] = (__bf16)hi;
  return __builtin_bit_cast(unsigned, t);
}

// ---------------- K0: stack + cast weights/bias to bf16 ----------------
__global__ __launch_bounds__(256) void prep_w(
    const float* __restrict__ Wq, const float* __restrict__ bq,
    const float* __restrict__ Wk, const float* __restrict__ bk,
    const float* __restrict__ Wv, const float* __restrict__ bv,
    u16* __restrict__ Wall, float* __restrict__ ball){
  int e = blockIdx.x * 256 + threadIdx.x;
  if (e < R_ * C_){
    int r = e >> 9, c = e & (C_ - 1);
    float w;
    if (r < 64)       w = Wq[r * C_ + c];
    else if (r < 128) w = Wk[(r - 64) * C_ + c];
    else              w = Wv[(r - 128) * C_ + c];
    Wall[e] = f2b(w);
  }
  if (e < R_){
    float bb;
    if (e < 64)       bb = bq[e];
    else if (e < 128) bb = bk[e - 64];
    else              bb = bv[e - 128];
    ball[e] = bb;
  }
}

// ---------------- K1: x [b][c][w] f32 -> xbT [b][w][c] bf16 ----------------
__global__ __launch_bounds__(256) void xpose(const float* __restrict__ x,
                                             u16* __restrict__ xbT){
  __shared__ float t[32][33];
  int b = blockIdx.z, c0 = blockIdx.y * 32, w0 = blockIdx.x * 32;
  int tx = threadIdx.x & 31, ty = threadIdx.x >> 5;   // ty 0..7
  const float* xb = x + (size_t)b * C_ * W_;
  #pragma unroll
  for (int k = 0; k < 4; k++)
    t[ty + k * 8][tx] = xb[(size_t)(c0 + ty + k * 8) * W_ + w0 + tx];
  __syncthreads();
  u16* ob = xbT + (size_t)b * W_ * C_;
  #pragma unroll
  for (int k = 0; k < 4; k++)
    ob[(size_t)(w0 + ty + k * 8) * C_ + c0 + tx] = f2b(t[tx][ty + k * 8]);
}

// ---------------- K2: fused projection GEMM ----------------
// Y[r][w] = sum_c Wall[r][c] * x[c][w] + ball[r], per batch.
// r<64 -> q_t[w][r] ; 64<=r<128 -> kT[w][r-64] ; else v[r-128][w] (plain)
#define PADW 40
__global__ __launch_bounds__(256) void gemm_proj(
    const u16* __restrict__ Wall, const float* __restrict__ ball,
    const u16* __restrict__ xbT, u16* __restrict__ qt,
    u16* __restrict__ ktp, u16* __restrict__ vn){
  __shared__ u16 at[64][PADW];
  __shared__ u16 bt[64][PADW];
  int b = blockIdx.z;
  int m0 = blockIdx.y * 64, n0 = blockIdx.x * 64;
  int tid = threadIdx.x, lane = tid & 63, wid = tid >> 6;
  int wm = wid >> 1, wn = wid & 1;
  int g = lane >> 4, r = lane & 15;
  const u16* xb = xbT + (size_t)b * W_ * C_;
  f32x4 acc[2][2] = {};
  int srow = tid >> 2, sseg = (tid & 3) * 8;
  for (int kk = 0; kk < 16; kk++){
    int c0 = kk * 32;
    *(u16x8*)&at[srow][sseg] = *(const u16x8*)&Wall[(size_t)(m0 + srow) * C_ + c0 + sseg];
    *(u16x8*)&bt[srow][sseg] = *(const u16x8*)&xb[(size_t)(n0 + srow) * C_ + c0 + sseg];
    __syncthreads();
    bf16x8 a0 = ldb(&at[wm * 32 +  0 + r][g * 8]);
    bf16x8 a1 = ldb(&at[wm * 32 + 16 + r][g * 8]);
    bf16x8 b0 = ldb(&bt[wn * 32 +  0 + r][g * 8]);
    bf16x8 b1 = ldb(&bt[wn * 32 + 16 + r][g * 8]);
    acc[0][0] = mfma16(a0, b0, acc[0][0]);
    acc[0][1] = mfma16(a0, b1, acc[0][1]);
    acc[1][0] = mfma16(a1, b0, acc[1][0]);
    acc[1][1] = mfma16(a1, b1, acc[1][1]);
    __syncthreads();
  }
  // epilogue: bias + store in attention layouts
  #pragma unroll
  for (int i = 0; i < 2; i++){
    #pragma unroll
    for (int n = 0; n < 2; n++){
      int rbase = m0 + wm * 32 + i * 16 + g * 4;
      int wcol  = n0 + wn * 32 + n * 16 + r;
      if (m0 < 128){
        u16* base = (m0 == 0 ? qt : ktp) + (size_t)b * W_ * CO_;
        u16x4 pk;
        #pragma unroll
        for (int t = 0; t < 4; t++) pk[t] = f2b(acc[i][n][t] + ball[rbase + t]);
        *(u16x4*)&base[(size_t)wcol * CO_ + (rbase & 63)] = pk;
      } else {
        u16* vb = vn + (size_t)b * C_ * W_;
        #pragma unroll
        for (int t = 0; t < 4; t++)
          vb[(size_t)(rbase + t - 128) * W_ + wcol] = f2b(acc[i][n][t] + ball[rbase + t]);
      }
    }
  }
}

// ---------------- K3: register flash attention v4 (32x32 MFMA + permlane) ----
// 1024 blocks x 256 thr. b = bid&7 (XCD-L2). Wave: 32 i x 64 c (2 c-tiles).
// Swapped QK^T via mfma_32x32x16: S[j][i], j=(reg&3)+8*(reg>>2)+4*hi, i=lane&31.
// One softmax chain per 32x32 tile; all cross-lane via v_permlane32_swap_b32.
__global__ __launch_bounds__(256, 4) void attn4(
    const u16* __restrict__ qt, const u16* __restrict__ ktp,
    const u16* __restrict__ vn, const float* __restrict__ x,
    const float* __restrict__ gamma, float* __restrict__ out){
  int tid = threadIdx.x, lane = tid & 63, wv = tid >> 6;
  int bid = blockIdx.x;
  int b = bid & 7;
  int u = bid >> 3;                  // 0..127
  int i0 = (u & 63) * 32;
  int cbase = (u >> 6) * 256 + wv * 64;
  int li = lane & 31, hi = lane >> 5;
  const u16* qtb = qt  + (size_t)b * W_ * CO_;
  const u16* ktb = ktp + (size_t)b * W_ * CO_;
  const u16* vnb = vn  + (size_t)b * C_ * W_;

  // Q B-frags (n=i=i0+li, k=o=oc*16+8*hi+e): contiguous 16B
  bf16x8 fq[4];
  #pragma unroll
  for (int oc = 0; oc < 4; oc++)
    fq[oc] = ldb(&qtb[(size_t)(i0 + li) * CO_ + oc * 16 + hi * 8]);

  f32x16 acc0 = {}, acc1 = {};
  float m_r = -1e30f, l_r = 0.f;

  for (int j0 = 0; j0 < W_; j0 += 32){
    // K A-frags (m=j=j0+li, k=o)
    bf16x8 fk0 = ldb(&ktb[(size_t)(j0 + li) * CO_ +  0 + hi * 8]);
    bf16x8 fk1 = ldb(&ktb[(size_t)(j0 + li) * CO_ + 16 + hi * 8]);
    bf16x8 fk2 = ldb(&ktb[(size_t)(j0 + li) * CO_ + 32 + hi * 8]);
    bf16x8 fk3 = ldb(&ktb[(size_t)(j0 + li) * CO_ + 48 + hi * 8]);
    // V A-frags (m=c, k=j chunk): contiguous 16B from plain [c][j]
    bf16x8 fv00 = ldb(&vnb[(size_t)(cbase      + li) * W_ + j0 +  0 + hi * 8]);
    bf16x8 fv01 = ldb(&vnb[(size_t)(cbase      + li) * W_ + j0 + 16 + hi * 8]);
    bf16x8 fv10 = ldb(&vnb[(size_t)(cbase + 32 + li) * W_ + j0 +  0 + hi * 8]);
    bf16x8 fv11 = ldb(&vnb[(size_t)(cbase + 32 + li) * W_ + j0 + 16 + hi * 8]);
    // S^T = K . Q^T (32x32, K=64 over 4 chunks)
    f32x16 S = {};
    S = mfma32(fk0, fq[0], S);
    S = mfma32(fk1, fq[1], S);
    S = mfma32(fk2, fq[2], S);
    S = mfma32(fk3, fq[3], S);
    // row max (over this lane's 16 j's, then cross-half)
    float t0 = fmaxf(fmaxf(S[0], S[1]), fmaxf(S[2], S[3]));
    float t1 = fmaxf(fmaxf(S[4], S[5]), fmaxf(S[6], S[7]));
    float t2 = fmaxf(fmaxf(S[8], S[9]), fmaxf(S[10], S[11]));
    float t3 = fmaxf(fmaxf(S[12], S[13]), fmaxf(S[14], S[15]));
    float tm = red_max32(fmaxf(fmaxf(t0, t1), fmaxf(t2, t3)));
    // defer-max (T13): rescale only when max grew past threshold
    if (__any(tm > m_r + 8.f)){
      float mn = fmaxf(m_r, tm);
      float al = __expf(m_r - mn);
      #pragma unroll
      for (int t = 0; t < 16; t++){ acc0[t] *= al; acc1[t] *= al; }
      l_r *= al; m_r = mn;
    }
    float p[16];
    #pragma unroll
    for (int t = 0; t < 16; t++) p[t] = __expf(S[t] - m_r);
    float s0 = (p[0] + p[1]) + (p[2] + p[3]);
    float s1 = (p[4] + p[5]) + (p[6] + p[7]);
    float s2 = (p[8] + p[9]) + (p[10] + p[11]);
    float s3 = (p[12] + p[13]) + (p[14] + p[15]);
    l_r += red_sum32((s0 + s1) + (s2 + s3));
    // pack P into PV B-frags (T12): 8 cvt_pk + 4 permlane32_swap
    unsigned A0 = pkbf(p[0], p[1]),  A1 = pkbf(p[2], p[3]);
    unsigned B0 = pkbf(p[4], p[5]),  B1 = pkbf(p[6], p[7]);
    unsigned C0 = pkbf(p[8], p[9]),  C1 = pkbf(p[10], p[11]);
    unsigned D0 = pkbf(p[12], p[13]), D1 = pkbf(p[14], p[15]);
    pl32swap(A0, B0); pl32swap(A1, B1);
    pl32swap(C0, D0); pl32swap(C1, D1);
    u32x4 w0 = {A0, A1, B0, B1};
    u32x4 w1 = {C0, C1, D0, D1};
    bf16x8 pf0 = __builtin_bit_cast(bf16x8, w0);
    bf16x8 pf1 = __builtin_bit_cast(bf16x8, w1);
    // PV: acc[c-tile] += V[c][j-chunk] . P[j][i]
    acc0 = mfma32(fv00, pf0, acc0);
    acc0 = mfma32(fv01, pf1, acc0);
    acc1 = mfma32(fv10, pf0, acc1);
    acc1 = mfma32(fv11, pf1, acc1);
  }
  // epilogue: out[c][i] = gamma * acc/l + x[c][i]
  float gm = gamma[0];
  float iv = 1.f / l_r;
  const float* xb = x + (size_t)b * C_ * W_;
  float* ob = out + (size_t)b * C_ * W_;
  int icol = i0 + li;
  #pragma unroll
  for (int t = 0; t < 16; t++){
    int crow = (t & 3) + 8 * (t >> 2) + 4 * hi;
    int c0 = cbase + crow, c1 = cbase + 32 + crow;
    ob[(size_t)c0 * W_ + icol] = gm * (acc0[t] * iv) + xb[(size_t)c0 * W_ + icol];
    ob[(size_t)c1 * W_ + icol] = gm * (acc1[t] * iv) + xb[(size_t)c1 * W_ + icol];
  }
}

extern "C" void kernel_launch(void* const* d_in, const int* in_sizes, int n_in,
                              void* d_out, int out_size, void* d_ws, size_t ws_size,
                              hipStream_t stream) {
  const float* x     = (const float*)d_in[0];
  const float* Wq    = (const float*)d_in[1];
  const float* bq    = (const float*)d_in[2];
  const float* Wk    = (const float*)d_in[3];
  const float* bk    = (const float*)d_in[4];
  const float* Wv    = (const float*)d_in[5];
  const float* bv    = (const float*)d_in[6];
  const float* gamma = (const float*)d_in[7];
  float* out = (float*)d_out;
  char* ws = (char*)d_ws;
  // workspace layout (~38.4 MB total)
  u16*   Wall = (u16*)  (ws + 0);         // 640*512*2        = 655360
  float* ball = (float*)(ws + 655360);    // 640*4            = 2560
  u16*   xbT  = (u16*)  (ws + 657920);    // 8*2048*512*2     = 16777216
  u16*   qt   = (u16*)  (ws + 17435136);  // 8*2048*64*2      = 2097152
  u16*   ktp  = (u16*)  (ws + 19532288);  // 8*2048*64*2      = 2097152
  u16*   vn   = (u16*)  (ws + 21629440);  // 8*512*2048*2     = 16777216

  prep_w<<<dim3(1280), dim3(256), 0, stream>>>(Wq, bq, Wk, bk, Wv, bv, Wall, ball);
  xpose<<<dim3(64, 16, 8), dim3(256), 0, stream>>>(x, xbT);
  gemm_proj<<<dim3(32, 10, 8), dim3(256), 0, stream>>>(Wall, ball, xbT, qt, ktp, vn);
  attn4<<<dim3(1024), dim3(256), 0, stream>>>(qt, ktp, vn, x, gamma, out);
}

// Round 5
// 151.056 us; speedup vs baseline: 1.8548x; 1.8548x over previous
//
#include <hip/hip_runtime.h>
#include <stdint.h>

// Problem constants (SelfAttention: B=8, C=512, C8=64, W=2048)
#define B_  8
#define C_  512
#define CO_ 64
#define W_  2048
#define R_  640   // stacked projection rows: 64 q + 64 k + 512 v

typedef float f32x4 __attribute__((ext_vector_type(4)));
typedef float f32x16 __attribute__((ext_vector_type(16)));
typedef __bf16 bf16x8 __attribute__((ext_vector_type(8)));
typedef __bf16 bf16x2 __attribute__((ext_vector_type(2)));
typedef unsigned u32x4 __attribute__((ext_vector_type(4)));
typedef unsigned short u16;
typedef u16 u16x8 __attribute__((ext_vector_type(8)));
typedef u16 u16x4 __attribute__((ext_vector_type(4)));

static __device__ __forceinline__ u16 f2b(float f){
  union { float f; unsigned u; } v; v.f = f;
  unsigned r = v.u + 0x7FFFu + ((v.u >> 16) & 1u);  // RNE
  return (u16)(r >> 16);
}
static __device__ __forceinline__ bf16x8 ldb(const u16* p){
  return __builtin_bit_cast(bf16x8, *(const u16x8*)p);
}
static __device__ __forceinline__ f32x4 mfma16(bf16x8 a, bf16x8 b, f32x4 c){
  return __builtin_amdgcn_mfma_f32_16x16x32_bf16(a, b, c, 0, 0, 0);
}
static __device__ __forceinline__ f32x16 mfma32(bf16x8 a, bf16x8 b, f32x16 c){
  return __builtin_amdgcn_mfma_f32_32x32x16_bf16(a, b, c, 0, 0, 0);
}
// v_permlane32_swap_b32: vdst lanes[32:63] <-> vsrc lanes[0:31]
static __device__ __forceinline__ void pl32swap(unsigned &a, unsigned &b){
  asm("v_permlane32_swap_b32 %0, %1" : "+v"(a), "+v"(b));
}
static __device__ __forceinline__ float red_max32(float v){
  unsigned a = __builtin_bit_cast(unsigned, v), b = a;
  pl32swap(a, b);
  return fmaxf(__builtin_bit_cast(float, a), __builtin_bit_cast(float, b));
}
static __device__ __forceinline__ float red_sum32(float v){
  unsigned a = __builtin_bit_cast(unsigned, v), b = a;
  pl32swap(a, b);
  return __builtin_bit_cast(float, a) + __builtin_bit_cast(float, b);
}
static __device__ __forceinline__ unsigned pkbf(float lo, float hi){
  bf16x2 t; t[0] = (__bf16)lo; t[1] = (__bf16)hi;
  return __builtin_bit_cast(unsigned, t);
}

// ---------------- K0: stack + cast weights/bias to bf16 ----------------
__global__ __launch_bounds__(256) void prep_w(
    const float* __restrict__ Wq, const float* __restrict__ bq,
    const float* __restrict__ Wk, const float* __restrict__ bk,
    const float* __restrict__ Wv, const float* __restrict__ bv,
    u16* __restrict__ Wall, float* __restrict__ ball){
  int e = blockIdx.x * 256 + threadIdx.x;
  if (e < R_ * C_){
    int r = e >> 9, c = e & (C_ - 1);
    float w;
    if (r < 64)       w = Wq[r * C_ + c];
    else if (r < 128) w = Wk[(r - 64) * C_ + c];
    else              w = Wv[(r - 128) * C_ + c];
    Wall[e] = f2b(w);
  }
  if (e < R_){
    float bb;
    if (e < 64)       bb = bq[e];
    else if (e < 128) bb = bk[e - 64];
    else              bb = bv[e - 128];
    ball[e] = bb;
  }
}

// ---------------- K1: x [b][c][w] f32 -> xbT [b][w][c] bf16 ----------------
__global__ __launch_bounds__(256) void xpose(const float* __restrict__ x,
                                             u16* __restrict__ xbT){
  __shared__ float t[32][33];
  int b = blockIdx.z, c0 = blockIdx.y * 32, w0 = blockIdx.x * 32;
  int tx = threadIdx.x & 31, ty = threadIdx.x >> 5;   // ty 0..7
  const float* xb = x + (size_t)b * C_ * W_;
  #pragma unroll
  for (int k = 0; k < 4; k++)
    t[ty + k * 8][tx] = xb[(size_t)(c0 + ty + k * 8) * W_ + w0 + tx];
  __syncthreads();
  u16* ob = xbT + (size_t)b * W_ * C_;
  #pragma unroll
  for (int k = 0; k < 4; k++)
    ob[(size_t)(w0 + ty + k * 8) * C_ + c0 + tx] = f2b(t[tx][ty + k * 8]);
}

// ---------------- K2: fused projection GEMM ----------------
// Y[r][w] = sum_c Wall[r][c] * x[c][w] + ball[r], per batch.
// Outputs stored FRAGMENT-MAJOR for the attention kernel's 32x32 MFMA:
//  Q/K: f[(w/32)][(o/16)][lane=((o>>3)&1)*32 + (w&31)][e=o&7]  (1KB/frag)
//  V:   f[(c/32)][(j/16)][lane=((j>>3)&1)*32 + (c&31)][e=j&7]  (1KB/frag)
// so every attn fragment load is one contiguous 64-lane dwordx4.
#define PADW 40
__global__ __launch_bounds__(256) void gemm_proj(
    const u16* __restrict__ Wall, const float* __restrict__ ball,
    const u16* __restrict__ xbT, u16* __restrict__ qf,
    u16* __restrict__ kf, u16* __restrict__ vf){
  __shared__ u16 at[64][PADW];
  __shared__ u16 bt[64][PADW];
  int b = blockIdx.z;
  int m0 = blockIdx.y * 64, n0 = blockIdx.x * 64;
  int tid = threadIdx.x, lane = tid & 63, wid = tid >> 6;
  int wm = wid >> 1, wn = wid & 1;
  int g = lane >> 4, r = lane & 15;
  const u16* xb = xbT + (size_t)b * W_ * C_;
  f32x4 acc[2][2] = {};
  int srow = tid >> 2, sseg = (tid & 3) * 8;
  for (int kk = 0; kk < 16; kk++){
    int c0 = kk * 32;
    *(u16x8*)&at[srow][sseg] = *(const u16x8*)&Wall[(size_t)(m0 + srow) * C_ + c0 + sseg];
    *(u16x8*)&bt[srow][sseg] = *(const u16x8*)&xb[(size_t)(n0 + srow) * C_ + c0 + sseg];
    __syncthreads();
    bf16x8 a0 = ldb(&at[wm * 32 +  0 + r][g * 8]);
    bf16x8 a1 = ldb(&at[wm * 32 + 16 + r][g * 8]);
    bf16x8 b0 = ldb(&bt[wn * 32 +  0 + r][g * 8]);
    bf16x8 b1 = ldb(&bt[wn * 32 + 16 + r][g * 8]);
    acc[0][0] = mfma16(a0, b0, acc[0][0]);
    acc[0][1] = mfma16(a0, b1, acc[0][1]);
    acc[1][0] = mfma16(a1, b0, acc[1][0]);
    acc[1][1] = mfma16(a1, b1, acc[1][1]);
    __syncthreads();
  }
  // epilogue: bias + store fragment-major
  #pragma unroll
  for (int i = 0; i < 2; i++){
    #pragma unroll
    for (int n = 0; n < 2; n++){
      int rbase = m0 + wm * 32 + i * 16 + g * 4;       // stacked row (o or c+128)
      int wcol  = n0 + wn * 32 + n * 16 + r;           // w (i or j)
      if (m0 < 128){
        u16* base = (m0 == 0 ? qf : kf) + (size_t)b * W_ * CO_;
        int o0 = (rbase & 63);                          // g*4 within 64, +t
        int oc = o0 >> 4, h2 = (o0 >> 3) & 1, e0 = o0 & 7;
        u16x4 pk;
        #pragma unroll
        for (int t = 0; t < 4; t++) pk[t] = f2b(acc[i][n][t] + ball[rbase + t]);
        *(u16x4*)&base[((size_t)((wcol >> 5) * 4 + oc) * 64 + h2 * 32 + (wcol & 31)) * 8 + e0] = pk;
      } else {
        u16* vb = vf + (size_t)b * C_ * W_;
        int jt = wcol >> 4, h2 = (wcol >> 3) & 1, e = wcol & 7;
        #pragma unroll
        for (int t = 0; t < 4; t++){
          int c = rbase + t - 128;
          vb[((size_t)((c >> 5) * (W_ / 16) + jt) * 64 + h2 * 32 + (c & 31)) * 8 + e] =
              f2b(acc[i][n][t] + ball[rbase + t]);
        }
      }
    }
  }
}

// ---------------- K3: register flash attention v5 (fragment-major loads) ----
// Identical structure to v4 (32x32 MFMA + permlane softmax); only the Q/K/V
// global layouts changed so every fragment load is one coalesced 1KB dwordx4.
__global__ __launch_bounds__(256, 4) void attn5(
    const u16* __restrict__ qf, const u16* __restrict__ kf,
    const u16* __restrict__ vf, const float* __restrict__ x,
    const float* __restrict__ gamma, float* __restrict__ out){
  int tid = threadIdx.x, lane = tid & 63, wv = tid >> 6;
  int bid = blockIdx.x;
  int b = bid & 7;
  int u = bid >> 3;                  // 0..127
  int i0 = (u & 63) * 32;
  int cbase = (u >> 6) * 256 + wv * 64;
  int li = lane & 31, hi = lane >> 5;
  const u16* qfb = qf + (size_t)b * W_ * CO_;
  const u16* kfb = kf + (size_t)b * W_ * CO_;
  const u16* vfb = vf + (size_t)b * C_ * W_;

  // Q B-frags: qf[(i0/32)][oc][lane][8]
  bf16x8 fq[4];
  const u16* qp = &qfb[(size_t)(i0 >> 5) * 4 * 512 + lane * 8];
  #pragma unroll
  for (int oc = 0; oc < 4; oc++) fq[oc] = ldb(qp + oc * 512);

  // V frag base offsets (c-tiles cbase/32 and cbase/32+1)
  const u16* vp0 = &vfb[(size_t)(cbase >> 5) * (W_ / 16) * 512 + lane * 8];
  const u16* vp1 = vp0 + (size_t)(W_ / 16) * 512;

  f32x16 acc0 = {}, acc1 = {};
  float m_r = -1e30f, l_r = 0.f;

  for (int j0 = 0; j0 < W_; j0 += 32){
    // K A-frags: kf[(j0/32)][oc][lane][8] — 4 contiguous 1KB loads
    const u16* kp = &kfb[(size_t)(j0 >> 5) * 4 * 512 + lane * 8];
    bf16x8 fk0 = ldb(kp +    0);
    bf16x8 fk1 = ldb(kp +  512);
    bf16x8 fk2 = ldb(kp + 1024);
    bf16x8 fk3 = ldb(kp + 1536);
    // V A-frags: vf[ct][(j0/16)+jc][lane][8] — 4 contiguous 1KB loads
    bf16x8 fv00 = ldb(vp0 + (size_t)(j0 >> 4) * 512);
    bf16x8 fv01 = ldb(vp0 + (size_t)((j0 >> 4) + 1) * 512);
    bf16x8 fv10 = ldb(vp1 + (size_t)(j0 >> 4) * 512);
    bf16x8 fv11 = ldb(vp1 + (size_t)((j0 >> 4) + 1) * 512);
    // S^T = K . Q^T (32x32, K=64 over 4 chunks)
    f32x16 S = {};
    S = mfma32(fk0, fq[0], S);
    S = mfma32(fk1, fq[1], S);
    S = mfma32(fk2, fq[2], S);
    S = mfma32(fk3, fq[3], S);
    // row max (this lane's 16 j's, then cross-half swap)
    float t0 = fmaxf(fmaxf(S[0], S[1]), fmaxf(S[2], S[3]));
    float t1 = fmaxf(fmaxf(S[4], S[5]), fmaxf(S[6], S[7]));
    float t2 = fmaxf(fmaxf(S[8], S[9]), fmaxf(S[10], S[11]));
    float t3 = fmaxf(fmaxf(S[12], S[13]), fmaxf(S[14], S[15]));
    float tm = red_max32(fmaxf(fmaxf(t0, t1), fmaxf(t2, t3)));
    // defer-max (T13)
    if (__any(tm > m_r + 8.f)){
      float mn = fmaxf(m_r, tm);
      float al = __expf(m_r - mn);
      #pragma unroll
      for (int t = 0; t < 16; t++){ acc0[t] *= al; acc1[t] *= al; }
      l_r *= al; m_r = mn;
    }
    float p[16];
    #pragma unroll
    for (int t = 0; t < 16; t++) p[t] = __expf(S[t] - m_r);
    float s0 = (p[0] + p[1]) + (p[2] + p[3]);
    float s1 = (p[4] + p[5]) + (p[6] + p[7]);
    float s2 = (p[8] + p[9]) + (p[10] + p[11]);
    float s3 = (p[12] + p[13]) + (p[14] + p[15]);
    l_r += red_sum32((s0 + s1) + (s2 + s3));
    // pack P into PV B-frags (T12): 8 cvt_pk + 4 permlane32_swap
    unsigned A0 = pkbf(p[0], p[1]),  A1 = pkbf(p[2], p[3]);
    unsigned B0 = pkbf(p[4], p[5]),  B1 = pkbf(p[6], p[7]);
    unsigned C0 = pkbf(p[8], p[9]),  C1 = pkbf(p[10], p[11]);
    unsigned D0 = pkbf(p[12], p[13]), D1 = pkbf(p[14], p[15]);
    pl32swap(A0, B0); pl32swap(A1, B1);
    pl32swap(C0, D0); pl32swap(C1, D1);
    u32x4 w0 = {A0, A1, B0, B1};
    u32x4 w1 = {C0, C1, D0, D1};
    bf16x8 pf0 = __builtin_bit_cast(bf16x8, w0);
    bf16x8 pf1 = __builtin_bit_cast(bf16x8, w1);
    // PV: acc[c-tile] += V[c][j-chunk] . P[j][i]
    acc0 = mfma32(fv00, pf0, acc0);
    acc0 = mfma32(fv01, pf1, acc0);
    acc1 = mfma32(fv10, pf0, acc1);
    acc1 = mfma32(fv11, pf1, acc1);
  }
  // epilogue: out[c][i] = gamma * acc/l + x[c][i]
  float gm = gamma[0];
  float iv = 1.f / l_r;
  const float* xb = x + (size_t)b * C_ * W_;
  float* ob = out + (size_t)b * C_ * W_;
  int icol = i0 + li;
  #pragma unroll
  for (int t = 0; t < 16; t++){
    int crow = (t & 3) + 8 * (t >> 2) + 4 * hi;
    int c0 = cbase + crow, c1 = cbase + 32 + crow;
    ob[(size_t)c0 * W_ + icol] = gm * (acc0[t] * iv) + xb[(size_t)c0 * W_ + icol];
    ob[(size_t)c1 * W_ + icol] = gm * (acc1[t] * iv) + xb[(size_t)c1 * W_ + icol];
  }
}

extern "C" void kernel_launch(void* const* d_in, const int* in_sizes, int n_in,
                              void* d_out, int out_size, void* d_ws, size_t ws_size,
                              hipStream_t stream) {
  const float* x     = (const float*)d_in[0];
  const float* Wq    = (const float*)d_in[1];
  const float* bq    = (const float*)d_in[2];
  const float* Wk    = (const float*)d_in[3];
  const float* bk    = (const float*)d_in[4];
  const float* Wv    = (const float*)d_in[5];
  const float* bv    = (const float*)d_in[6];
  const float* gamma = (const float*)d_in[7];
  float* out = (float*)d_out;
  char* ws = (char*)d_ws;
  // workspace layout (~38.4 MB total)
  u16*   Wall = (u16*)  (ws + 0);         // 640*512*2        = 655360
  float* ball = (float*)(ws + 655360);    // 640*4            = 2560
  u16*   xbT  = (u16*)  (ws + 657920);    // 8*2048*512*2     = 16777216
  u16*   qf   = (u16*)  (ws + 17435136);  // 8*2048*64*2      = 2097152
  u16*   kf   = (u16*)  (ws + 19532288);  // 8*2048*64*2      = 2097152
  u16*   vf   = (u16*)  (ws + 21629440);  // 8*512*2048*2     = 16777216

  prep_w<<<dim3(1280), dim3(256), 0, stream>>>(Wq, bq, Wk, bk, Wv, bv, Wall, ball);
  xpose<<<dim3(64, 16, 8), dim3(256), 0, stream>>>(x, xbT);
  gemm_proj<<<dim3(32, 10, 8), dim3(256), 0, stream>>>(Wall, ball, xbT, qf, kf, vf);
  attn5<<<dim3(1024), dim3(256), 0, stream>>>(qf, kf, vf, x, gamma, out);
}

// Round 7
// 124.533 us; speedup vs baseline: 2.2498x; 1.2130x over previous
//
#include <hip/hip_runtime.h>
#include <stdint.h>

// Problem constants (SelfAttention: B=8, C=512, C8=64, W=2048)
#define B_  8
#define C_  512
#define CO_ 64
#define W_  2048
#define R_  640   // stacked projection rows: 64 q + 64 k + 512 v
#define LOG2E 1.4426950408889634f

typedef float f32x4 __attribute__((ext_vector_type(4)));
typedef float f32x16 __attribute__((ext_vector_type(16)));
typedef __bf16 bf16x8 __attribute__((ext_vector_type(8)));
typedef __bf16 bf16x2 __attribute__((ext_vector_type(2)));
typedef unsigned u32x4 __attribute__((ext_vector_type(4)));
typedef unsigned short u16;
typedef u16 u16x8 __attribute__((ext_vector_type(8)));
typedef u16 u16x4 __attribute__((ext_vector_type(4)));

static __device__ __forceinline__ float exp2g(float f){
  return __builtin_amdgcn_exp2f(f);    // v_exp_f32 (2^x)
}
static __device__ __forceinline__ u16 f2b(float f){
  union { float f; unsigned u; } v; v.f = f;
  unsigned r = v.u + 0x7FFFu + ((v.u >> 16) & 1u);  // RNE
  return (u16)(r >> 16);
}
static __device__ __forceinline__ bf16x8 ldb(const u16* p){
  return __builtin_bit_cast(bf16x8, *(const u16x8*)p);
}
static __device__ __forceinline__ f32x4 mfma16(bf16x8 a, bf16x8 b, f32x4 c){
  return __builtin_amdgcn_mfma_f32_16x16x32_bf16(a, b, c, 0, 0, 0);
}
static __device__ __forceinline__ f32x16 mfma32(bf16x8 a, bf16x8 b, f32x16 c){
  return __builtin_amdgcn_mfma_f32_32x32x16_bf16(a, b, c, 0, 0, 0);
}
// v_permlane32_swap_b32: vdst lanes[32:63] <-> vsrc lanes[0:31]
static __device__ __forceinline__ void pl32swap(unsigned &a, unsigned &b){
  asm("v_permlane32_swap_b32 %0, %1" : "+v"(a), "+v"(b));
}
static __device__ __forceinline__ float red_max32(float v){
  unsigned a = __builtin_bit_cast(unsigned, v), b = a;
  pl32swap(a, b);
  return fmaxf(__builtin_bit_cast(float, a), __builtin_bit_cast(float, b));
}
static __device__ __forceinline__ float red_sum32(float v){
  unsigned a = __builtin_bit_cast(unsigned, v), b = a;
  pl32swap(a, b);
  return __builtin_bit_cast(float, a) + __builtin_bit_cast(float, b);
}
static __device__ __forceinline__ unsigned pkbf(float lo, float hi){
  bf16x2 t; t[0] = (__bf16)lo; t[1] = (__bf16)hi;
  return __builtin_bit_cast(unsigned, t);
}

// ---------------- K0: stack + cast weights/bias to bf16 ----------------
// Q rows are pre-scaled by log2(e) so attention softmax can use raw exp2.
__global__ __launch_bounds__(256) void prep_w(
    const float* __restrict__ Wq, const float* __restrict__ bq,
    const float* __restrict__ Wk, const float* __restrict__ bk,
    const float* __restrict__ Wv, const float* __restrict__ bv,
    u16* __restrict__ Wall, float* __restrict__ ball){
  int e = blockIdx.x * 256 + threadIdx.x;
  if (e < R_ * C_){
    int r = e >> 9, c = e & (C_ - 1);
    float w;
    if (r < 64)       w = Wq[r * C_ + c] * LOG2E;
    else if (r < 128) w = Wk[(r - 64) * C_ + c];
    else              w = Wv[(r - 128) * C_ + c];
    Wall[e] = f2b(w);
  }
  if (e < R_){
    float bb;
    if (e < 64)       bb = bq[e] * LOG2E;
    else if (e < 128) bb = bk[e - 64];
    else              bb = bv[e - 128];
    ball[e] = bb;
  }
}

// ---------------- K1: x [b][c][w] f32 -> xbT [b][w][c] bf16 ----------------
__global__ __launch_bounds__(256) void xpose(const float* __restrict__ x,
                                             u16* __restrict__ xbT){
  __shared__ float t[32][33];
  int b = blockIdx.z, c0 = blockIdx.y * 32, w0 = blockIdx.x * 32;
  int tx = threadIdx.x & 31, ty = threadIdx.x >> 5;   // ty 0..7
  const float* xb = x + (size_t)b * C_ * W_;
  #pragma unroll
  for (int k = 0; k < 4; k++)
    t[ty + k * 8][tx] = xb[(size_t)(c0 + ty + k * 8) * W_ + w0 + tx];
  __syncthreads();
  u16* ob = xbT + (size_t)b * W_ * C_;
  #pragma unroll
  for (int k = 0; k < 4; k++)
    ob[(size_t)(w0 + ty + k * 8) * C_ + c0 + tx] = f2b(t[tx][ty + k * 8]);
}

// ---------------- K2: fused projection GEMM ----------------
// Y[r][w] = sum_c Wall[r][c] * x[c][w] + ball[r], per batch.
// Outputs stored FRAGMENT-MAJOR for the attention kernel's 32x32 MFMA:
//  Q/K: f[(w/32)][(o/16)][lane=((o>>3)&1)*32 + (w&31)][e=o&7]  (1KB/frag)
//  V:   f[(c/32)][(j/16)][lane=((j>>3)&1)*32 + (c&31)][e=j&7]  (1KB/frag)
#define PADW 40
__global__ __launch_bounds__(256) void gemm_proj(
    const u16* __restrict__ Wall, const float* __restrict__ ball,
    const u16* __restrict__ xbT, u16* __restrict__ qf,
    u16* __restrict__ kf, u16* __restrict__ vf){
  __shared__ u16 at[64][PADW];
  __shared__ u16 bt[64][PADW];
  int b = blockIdx.z;
  int m0 = blockIdx.y * 64, n0 = blockIdx.x * 64;
  int tid = threadIdx.x, lane = tid & 63, wid = tid >> 6;
  int wm = wid >> 1, wn = wid & 1;
  int g = lane >> 4, r = lane & 15;
  const u16* xb = xbT + (size_t)b * W_ * C_;
  f32x4 acc[2][2] = {};
  int srow = tid >> 2, sseg = (tid & 3) * 8;
  for (int kk = 0; kk < 16; kk++){
    int c0 = kk * 32;
    *(u16x8*)&at[srow][sseg] = *(const u16x8*)&Wall[(size_t)(m0 + srow) * C_ + c0 + sseg];
    *(u16x8*)&bt[srow][sseg] = *(const u16x8*)&xb[(size_t)(n0 + srow) * C_ + c0 + sseg];
    __syncthreads();
    bf16x8 a0 = ldb(&at[wm * 32 +  0 + r][g * 8]);
    bf16x8 a1 = ldb(&at[wm * 32 + 16 + r][g * 8]);
    bf16x8 b0 = ldb(&bt[wn * 32 +  0 + r][g * 8]);
    bf16x8 b1 = ldb(&bt[wn * 32 + 16 + r][g * 8]);
    acc[0][0] = mfma16(a0, b0, acc[0][0]);
    acc[0][1] = mfma16(a0, b1, acc[0][1]);
    acc[1][0] = mfma16(a1, b0, acc[1][0]);
    acc[1][1] = mfma16(a1, b1, acc[1][1]);
    __syncthreads();
  }
  // epilogue: bias + store fragment-major
  #pragma unroll
  for (int i = 0; i < 2; i++){
    #pragma unroll
    for (int n = 0; n < 2; n++){
      int rbase = m0 + wm * 32 + i * 16 + g * 4;       // stacked row (o or c+128)
      int wcol  = n0 + wn * 32 + n * 16 + r;           // w (i or j)
      if (m0 < 128){
        u16* base = (m0 == 0 ? qf : kf) + (size_t)b * W_ * CO_;
        int o0 = (rbase & 63);
        int oc = o0 >> 4, h2 = (o0 >> 3) & 1, e0 = o0 & 7;
        u16x4 pk;
        #pragma unroll
        for (int t = 0; t < 4; t++) pk[t] = f2b(acc[i][n][t] + ball[rbase + t]);
        *(u16x4*)&base[((size_t)((wcol >> 5) * 4 + oc) * 64 + h2 * 32 + (wcol & 31)) * 8 + e0] = pk;
      } else {
        u16* vb = vf + (size_t)b * C_ * W_;
        int jt = wcol >> 4, h2 = (wcol >> 3) & 1, e = wcol & 7;
        #pragma unroll
        for (int t = 0; t < 4; t++){
          int c = rbase + t - 128;
          vb[((size_t)((c >> 5) * (W_ / 16) + jt) * 64 + h2 * 32 + (c & 31)) * 8 + e] =
              f2b(acc[i][n][t] + ball[rbase + t]);
        }
      }
    }
  }
}

// ---------------- K3: register flash attention v6 ----------------
// 512 blocks x 256 thr. b = bid&7, i0 = (bid>>3)*32. 4 waves share (b,i0);
// wave wv owns c-range [wv*128, wv*128+128) (4 c-tiles, 64 AGPR acc).
// K/Q frag loads shared within block (L1-amortized). Double-buffered
// fragment prefetch hides latency at 2 waves/SIMD. Softmax in exp2 domain.
__global__ __launch_bounds__(256, 2) void attn6(
    const u16* __restrict__ qf, const u16* __restrict__ kf,
    const u16* __restrict__ vf, const float* __restrict__ x,
    const float* __restrict__ gamma, float* __restrict__ out){
  int tid = threadIdx.x, lane = tid & 63, wv = tid >> 6;
  int bid = blockIdx.x;
  int b = bid & 7;
  int i0 = (bid >> 3) * 32;
  int cbase = wv * 128;
  int li = lane & 31, hi = lane >> 5;
  const u16* qfb = qf + (size_t)b * W_ * CO_;
  const u16* kfb = kf + (size_t)b * W_ * CO_;
  const u16* vfb = vf + (size_t)b * C_ * W_;

  // Q B-frags: qf[(i0/32)][oc][lane][8]
  bf16x8 fq[4];
  const u16* qp = &qfb[(size_t)(i0 >> 5) * 4 * 512 + lane * 8];
  #pragma unroll
  for (int oc = 0; oc < 4; oc++) fq[oc] = ldb(qp + oc * 512);

  // V frag bases for the 4 c-tiles
  const u16* vp[4];
  #pragma unroll
  for (int ct = 0; ct < 4; ct++)
    vp[ct] = &vfb[(size_t)((cbase >> 5) + ct) * (W_ / 16) * 512 + lane * 8];
  const u16* kbase = &kfb[lane * 8];

  f32x16 acc[4] = {};
  float m_r = -1e30f, l_r = 0.f;

  // fragment buffers A (current) and B (next)
  bf16x8 fkA[4], fvA[4][2], fkB[4], fvB[4][2];
  #pragma unroll
  for (int oc = 0; oc < 4; oc++) fkA[oc] = ldb(kbase + (size_t)oc * 512);
  #pragma unroll
  for (int ct = 0; ct < 4; ct++){
    fvA[ct][0] = ldb(vp[ct]);
    fvA[ct][1] = ldb(vp[ct] + 512);
  }

  auto compute = [&](bf16x8 (&fk)[4], bf16x8 (&fv)[4][2]){
    f32x16 S = {};
    S = mfma32(fk[0], fq[0], S);
    S = mfma32(fk[1], fq[1], S);
    S = mfma32(fk[2], fq[2], S);
    S = mfma32(fk[3], fq[3], S);
    float t0 = fmaxf(fmaxf(S[0], S[1]), fmaxf(S[2], S[3]));
    float t1 = fmaxf(fmaxf(S[4], S[5]), fmaxf(S[6], S[7]));
    float t2 = fmaxf(fmaxf(S[8], S[9]), fmaxf(S[10], S[11]));
    float t3 = fmaxf(fmaxf(S[12], S[13]), fmaxf(S[14], S[15]));
    float tm = red_max32(fmaxf(fmaxf(t0, t1), fmaxf(t2, t3)));
    if (__any(tm > m_r + 8.f)){            // defer-max (T13), log2 domain
      float mn = fmaxf(m_r, tm);
      float al = exp2g(m_r - mn);
      #pragma unroll
      for (int ct = 0; ct < 4; ct++)
        #pragma unroll
        for (int t = 0; t < 16; t++) acc[ct][t] *= al;
      l_r *= al; m_r = mn;
    }
    float p[16];
    #pragma unroll
    for (int t = 0; t < 16; t++) p[t] = exp2g(S[t] - m_r);
    float s0 = (p[0] + p[1]) + (p[2] + p[3]);
    float s1 = (p[4] + p[5]) + (p[6] + p[7]);
    float s2 = (p[8] + p[9]) + (p[10] + p[11]);
    float s3 = (p[12] + p[13]) + (p[14] + p[15]);
    l_r += red_sum32((s0 + s1) + (s2 + s3));
    unsigned A0 = pkbf(p[0], p[1]),   A1 = pkbf(p[2], p[3]);
    unsigned B0 = pkbf(p[4], p[5]),   B1 = pkbf(p[6], p[7]);
    unsigned C0 = pkbf(p[8], p[9]),   C1 = pkbf(p[10], p[11]);
    unsigned D0 = pkbf(p[12], p[13]), D1 = pkbf(p[14], p[15]);
    pl32swap(A0, B0); pl32swap(A1, B1);
    pl32swap(C0, D0); pl32swap(C1, D1);
    u32x4 w0 = {A0, A1, B0, B1};
    u32x4 w1 = {C0, C1, D0, D1};
    bf16x8 pf0 = __builtin_bit_cast(bf16x8, w0);
    bf16x8 pf1 = __builtin_bit_cast(bf16x8, w1);
    #pragma unroll
    for (int ct = 0; ct < 4; ct++){
      acc[ct] = mfma32(fv[ct][0], pf0, acc[ct]);
      acc[ct] = mfma32(fv[ct][1], pf1, acc[ct]);
    }
  };

  for (int t = 0; t < 64; t += 2){
    // prefetch tile t+1 into B
    {
      const u16* kp = kbase + (size_t)(t + 1) * 4 * 512;
      #pragma unroll
      for (int oc = 0; oc < 4; oc++) fkB[oc] = ldb(kp + (size_t)oc * 512);
      #pragma unroll
      for (int ct = 0; ct < 4; ct++){
        fvB[ct][0] = ldb(vp[ct] + (size_t)(2 * t + 2) * 512);
        fvB[ct][1] = ldb(vp[ct] + (size_t)(2 * t + 3) * 512);
      }
    }
    compute(fkA, fvA);
    // prefetch tile t+2 into A
    if (t + 2 < 64){
      const u16* kp = kbase + (size_t)(t + 2) * 4 * 512;
      #pragma unroll
      for (int oc = 0; oc < 4; oc++) fkA[oc] = ldb(kp + (size_t)oc * 512);
      #pragma unroll
      for (int ct = 0; ct < 4; ct++){
        fvA[ct][0] = ldb(vp[ct] + (size_t)(2 * t + 4) * 512);
        fvA[ct][1] = ldb(vp[ct] + (size_t)(2 * t + 5) * 512);
      }
    }
    compute(fkB, fvB);
  }

  // epilogue: out[c][i] = gamma * acc/l + x[c][i]
  float gm = gamma[0];
  float iv = 1.f / l_r;
  const float* xb = x + (size_t)b * C_ * W_;
  float* ob = out + (size_t)b * C_ * W_;
  int icol = i0 + li;
  #pragma unroll
  for (int ct = 0; ct < 4; ct++){
    #pragma unroll
    for (int t = 0; t < 16; t++){
      int crow = (t & 3) + 8 * (t >> 2) + 4 * hi;
      int c = cbase + ct * 32 + crow;
      ob[(size_t)c * W_ + icol] = gm * (acc[ct][t] * iv) + xb[(size_t)c * W_ + icol];
    }
  }
}

extern "C" void kernel_launch(void* const* d_in, const int* in_sizes, int n_in,
                              void* d_out, int out_size, void* d_ws, size_t ws_size,
                              hipStream_t stream) {
  const float* x     = (const float*)d_in[0];
  const float* Wq    = (const float*)d_in[1];
  const float* bq    = (const float*)d_in[2];
  const float* Wk    = (const float*)d_in[3];
  const float* bk    = (const float*)d_in[4];
  const float* Wv    = (const float*)d_in[5];
  const float* bv    = (const float*)d_in[6];
  const float* gamma = (const float*)d_in[7];
  float* out = (float*)d_out;
  char* ws = (char*)d_ws;
  // workspace layout (~38.4 MB total)
  u16*   Wall = (u16*)  (ws + 0);         // 640*512*2        = 655360
  float* ball = (float*)(ws + 655360);    // 640*4            = 2560
  u16*   xbT  = (u16*)  (ws + 657920);    // 8*2048*512*2     = 16777216
  u16*   qf   = (u16*)  (ws + 17435136);  // 8*2048*64*2      = 2097152
  u16*   kf   = (u16*)  (ws + 19532288);  // 8*2048*64*2      = 2097152
  u16*   vf   = (u16*)  (ws + 21629440);  // 8*512*2048*2     = 16777216

  prep_w<<<dim3(1280), dim3(256), 0, stream>>>(Wq, bq, Wk, bk, Wv, bv, Wall, ball);
  xpose<<<dim3(64, 16, 8), dim3(256), 0, stream>>>(x, xbT);
  gemm_proj<<<dim3(32, 10, 8), dim3(256), 0, stream>>>(Wall, ball, xbT, qf, kf, vf);
  attn6<<<dim3(512), dim3(256), 0, stream>>>(qf, kf, vf, x, gamma, out);
}